// Round 7
// baseline (566.044 us; speedup 1.0000x reference)
//
#include <hip/hip_runtime.h>

typedef unsigned short u16;
typedef unsigned int u32;

#define B_ 4
#define S_ 2048
#define D_ 1024
#define H_ 16
#define HD_ 64
#define M_ (B_ * S_)    // 8192 rows
#define QK_ (2 * D_)    // 2048 (Q|K feature stride in qk ws)

typedef __bf16 bf16x8 __attribute__((ext_vector_type(8)));
typedef float f32x4 __attribute__((ext_vector_type(4)));

#define MASKVAL (-1.0e30f)

static __device__ __forceinline__ u16 f2bf(float f) {
    union { float f; u32 u; } v; v.f = f;
    u32 u = v.u;
    u32 r = (u + 0x7FFFu + ((u >> 16) & 1u)) >> 16;  // RNE
    return (u16)r;
}

// convert 8 fp32 -> 8 bf16, store 16B to LDS
static __device__ __forceinline__ void cvt8(const float4 a, const float4 b, u16* dst) {
    union { u16 h[8]; int4 v; } pk;
    pk.h[0] = f2bf(a.x); pk.h[1] = f2bf(a.y); pk.h[2] = f2bf(a.z); pk.h[3] = f2bf(a.w);
    pk.h[4] = f2bf(b.x); pk.h[5] = f2bf(b.y); pk.h[6] = f2bf(b.z); pk.h[7] = f2bf(b.w);
    *(int4*)dst = pk.v;
}

// C[M,N](bf16) = A[M,K](f32) * B[N,K](f32)^T, fp32 accum.
__global__ __launch_bounds__(256) void gemm_ff(const float* __restrict__ A,
                                               const float* __restrict__ Bw,
                                               u16* __restrict__ C,
                                               int Ndim, int Kdim) {
    __shared__ u16 Alds[128 * 72];
    __shared__ u16 Blds[128 * 72];
    const int t = threadIdx.x;
    const int bx = blockIdx.x, by = blockIdx.y;
    const int wave = t >> 6, lane = t & 63;
    const int ml = lane & 15, quad = lane >> 4;
    const int wm = (wave >> 1) * 64, wn = (wave & 1) * 64;
    const int rowA0 = by * 128, rowB0 = bx * 128;
    const int srow = t >> 3, sseg = (t & 7) * 8;

    f32x4 acc[4][4];
    const f32x4 zero = {0.f, 0.f, 0.f, 0.f};
#pragma unroll
    for (int i = 0; i < 4; ++i)
#pragma unroll
        for (int j = 0; j < 4; ++j) acc[i][j] = zero;

    for (int k0 = 0; k0 < Kdim; k0 += 64) {
        __syncthreads();
#pragma unroll
        for (int p = 0; p < 4; ++p) {
            int r = srow + p * 32;
            const float* ap = &A[(size_t)(rowA0 + r) * Kdim + k0 + sseg];
            const float* bp = &Bw[(size_t)(rowB0 + r) * Kdim + k0 + sseg];
            cvt8(*(const float4*)ap, *(const float4*)(ap + 4), &Alds[r * 72 + sseg]);
            cvt8(*(const float4*)bp, *(const float4*)(bp + 4), &Blds[r * 72 + sseg]);
        }
        __syncthreads();
#pragma unroll
        for (int kc = 0; kc < 2; ++kc) {
            bf16x8 a[4], b[4];
#pragma unroll
            for (int i = 0; i < 4; ++i)
                a[i] = *(const bf16x8*)(&Alds[(wm + i * 16 + ml) * 72 + kc * 32 + quad * 8]);
#pragma unroll
            for (int j = 0; j < 4; ++j)
                b[j] = *(const bf16x8*)(&Blds[(wn + j * 16 + ml) * 72 + kc * 32 + quad * 8]);
#pragma unroll
            for (int i = 0; i < 4; ++i)
#pragma unroll
                for (int j = 0; j < 4; ++j)
                    acc[i][j] = __builtin_amdgcn_mfma_f32_16x16x32_bf16(a[i], b[j], acc[i][j], 0, 0, 0);
        }
    }
#pragma unroll
    for (int i = 0; i < 4; ++i)
#pragma unroll
        for (int j = 0; j < 4; ++j)
#pragma unroll
            for (int r = 0; r < 4; ++r) {
                int row = rowA0 + wm + i * 16 + quad * 4 + r;
                int col = rowB0 + wn + j * 16 + ml;
                C[(size_t)row * Ndim + col] = f2bf(acc[i][j][r]);
            }
}

// V GEMM, fp32 in, transposed bf16 epilogue: Vt[(b*H+h)*64+hd][s]
__global__ __launch_bounds__(256) void gemm_vt(const float* __restrict__ A,
                                               const float* __restrict__ Bw,
                                               u16* __restrict__ Vt,
                                               int Kdim) {
    __shared__ u16 Alds[128 * 72];
    __shared__ u16 Blds[128 * 72];
    const int t = threadIdx.x;
    const int bx = blockIdx.x, by = blockIdx.y;
    const int wave = t >> 6, lane = t & 63;
    const int ml = lane & 15, quad = lane >> 4;
    const int wm = (wave >> 1) * 64, wn = (wave & 1) * 64;
    const int rowA0 = by * 128, rowB0 = bx * 128;
    const int srow = t >> 3, sseg = (t & 7) * 8;

    f32x4 acc[4][4];
    const f32x4 zero = {0.f, 0.f, 0.f, 0.f};
#pragma unroll
    for (int i = 0; i < 4; ++i)
#pragma unroll
        for (int j = 0; j < 4; ++j) acc[i][j] = zero;

    for (int k0 = 0; k0 < Kdim; k0 += 64) {
        __syncthreads();
#pragma unroll
        for (int p = 0; p < 4; ++p) {
            int r = srow + p * 32;
            const float* ap = &A[(size_t)(rowA0 + r) * Kdim + k0 + sseg];
            const float* bp = &Bw[(size_t)(rowB0 + r) * Kdim + k0 + sseg];
            cvt8(*(const float4*)ap, *(const float4*)(ap + 4), &Alds[r * 72 + sseg]);
            cvt8(*(const float4*)bp, *(const float4*)(bp + 4), &Blds[r * 72 + sseg]);
        }
        __syncthreads();
#pragma unroll
        for (int kc = 0; kc < 2; ++kc) {
            bf16x8 a[4], b[4];
#pragma unroll
            for (int i = 0; i < 4; ++i)
                a[i] = *(const bf16x8*)(&Alds[(wm + i * 16 + ml) * 72 + kc * 32 + quad * 8]);
#pragma unroll
            for (int j = 0; j < 4; ++j)
                b[j] = *(const bf16x8*)(&Blds[(wn + j * 16 + ml) * 72 + kc * 32 + quad * 8]);
#pragma unroll
            for (int i = 0; i < 4; ++i)
#pragma unroll
                for (int j = 0; j < 4; ++j)
                    acc[i][j] = __builtin_amdgcn_mfma_f32_16x16x32_bf16(a[i], b[j], acc[i][j], 0, 0, 0);
        }
    }
#pragma unroll
    for (int i = 0; i < 4; ++i)
#pragma unroll
        for (int j = 0; j < 4; ++j) {
            int row0 = rowA0 + wm + i * 16 + quad * 4;  // token, multiple of 4
            int col = rowB0 + wn + j * 16 + ml;         // V feature
            int b = row0 >> 11;
            int s0 = row0 & (S_ - 1);
            union { u16 h[4]; ushort4 v; } pk;
#pragma unroll
            for (int r = 0; r < 4; ++r) pk.h[r] = f2bf(acc[i][j][r]);
            *(ushort4*)(&Vt[((size_t)(b * D_ + col)) * S_ + s0]) = pk.v;
        }
}

// Proj GEMM: A bf16 [M,K], B fp32 [N,K], C **fp32** out (reference output dtype)
__global__ __launch_bounds__(256) void gemm_proj(const u16* __restrict__ A,
                                                 const float* __restrict__ Bw,
                                                 float* __restrict__ C,
                                                 int Ndim, int Kdim) {
    __shared__ u16 Alds[128 * 72];
    __shared__ u16 Blds[128 * 72];
    const int t = threadIdx.x;
    const int bx = blockIdx.x, by = blockIdx.y;
    const int wave = t >> 6, lane = t & 63;
    const int ml = lane & 15, quad = lane >> 4;
    const int wm = (wave >> 1) * 64, wn = (wave & 1) * 64;
    const int rowA0 = by * 128, rowB0 = bx * 128;
    const int srow = t >> 3, sseg = (t & 7) * 8;

    f32x4 acc[4][4];
    const f32x4 zero = {0.f, 0.f, 0.f, 0.f};
#pragma unroll
    for (int i = 0; i < 4; ++i)
#pragma unroll
        for (int j = 0; j < 4; ++j) acc[i][j] = zero;

    for (int k0 = 0; k0 < Kdim; k0 += 64) {
        __syncthreads();
#pragma unroll
        for (int p = 0; p < 4; ++p) {
            int r = srow + p * 32;
            *(int4*)(&Alds[r * 72 + sseg]) =
                *(const int4*)(&A[(size_t)(rowA0 + r) * Kdim + k0 + sseg]);
            const float* bp = &Bw[(size_t)(rowB0 + r) * Kdim + k0 + sseg];
            cvt8(*(const float4*)bp, *(const float4*)(bp + 4), &Blds[r * 72 + sseg]);
        }
        __syncthreads();
#pragma unroll
        for (int kc = 0; kc < 2; ++kc) {
            bf16x8 a[4], b[4];
#pragma unroll
            for (int i = 0; i < 4; ++i)
                a[i] = *(const bf16x8*)(&Alds[(wm + i * 16 + ml) * 72 + kc * 32 + quad * 8]);
#pragma unroll
            for (int j = 0; j < 4; ++j)
                b[j] = *(const bf16x8*)(&Blds[(wn + j * 16 + ml) * 72 + kc * 32 + quad * 8]);
#pragma unroll
            for (int i = 0; i < 4; ++i)
#pragma unroll
                for (int j = 0; j < 4; ++j)
                    acc[i][j] = __builtin_amdgcn_mfma_f32_16x16x32_bf16(a[i], b[j], acc[i][j], 0, 0, 0);
        }
    }
#pragma unroll
    for (int i = 0; i < 4; ++i)
#pragma unroll
        for (int j = 0; j < 4; ++j)
#pragma unroll
            for (int r = 0; r < 4; ++r) {
                int row = rowA0 + wm + i * 16 + quad * 4 + r;
                int col = rowB0 + wn + j * 16 + ml;
                C[(size_t)row * Ndim + col] = acc[i][j][r];   // fp32 store
            }
}

// Flash attention (cross-validated vs scalar reference in R3/R4).
__global__ __launch_bounds__(256) void attn(const u16* __restrict__ qk,
                                            const u16* __restrict__ Vt,
                                            u16* __restrict__ AO) {
    __shared__ u16 Plds[4][32 * 64];
    const int t = threadIdx.x;
    const int wave = t >> 6, lane = t & 63;
    const int ml = lane & 15, quad = lane >> 4;
    const int bid = blockIdx.x;
    const int qt = bid & 15;
    const int bh = bid >> 4;
    const int b = bh >> 4, h = bh & 15;
    const int qbase = qt * 128 + wave * 32;
    const size_t rowbase = (size_t)b * S_;

    bf16x8 qf[2][2];
#pragma unroll
    for (int mi = 0; mi < 2; ++mi)
#pragma unroll
        for (int kc = 0; kc < 2; ++kc)
            qf[mi][kc] = *(const bf16x8*)(&qk[(rowbase + qbase + mi * 16 + ml) * QK_ +
                                             h * HD_ + kc * 32 + quad * 8]);

    f32x4 o[2][4];
    float mr[2][4], lr[2][4];
    const f32x4 zero = {0.f, 0.f, 0.f, 0.f};
#pragma unroll
    for (int mi = 0; mi < 2; ++mi) {
#pragma unroll
        for (int nd = 0; nd < 4; ++nd) o[mi][nd] = zero;
#pragma unroll
        for (int r = 0; r < 4; ++r) { mr[mi][r] = MASKVAL; lr[mi][r] = 0.f; }
    }

    const int ktmax = (qbase + 31) >> 6;
    for (int kt = 0; kt <= ktmax; ++kt) {
        const int kb = kt * 64;
        bf16x8 kf[4][2];
#pragma unroll
        for (int ni = 0; ni < 4; ++ni)
#pragma unroll
            for (int kc = 0; kc < 2; ++kc)
                kf[ni][kc] = *(const bf16x8*)(&qk[(rowbase + kb + ni * 16 + ml) * QK_ +
                                                  D_ + h * HD_ + kc * 32 + quad * 8]);
        f32x4 sc[2][4];
#pragma unroll
        for (int mi = 0; mi < 2; ++mi)
#pragma unroll
            for (int ni = 0; ni < 4; ++ni) {
                f32x4 s = zero;
#pragma unroll
                for (int kc = 0; kc < 2; ++kc)
                    s = __builtin_amdgcn_mfma_f32_16x16x32_bf16(qf[mi][kc], kf[ni][kc], s, 0, 0, 0);
                sc[mi][ni] = s;
            }
#pragma unroll
        for (int mi = 0; mi < 2; ++mi)
#pragma unroll
            for (int ni = 0; ni < 4; ++ni)
#pragma unroll
                for (int r = 0; r < 4; ++r) {
                    int q = qbase + mi * 16 + quad * 4 + r;
                    int k = kb + ni * 16 + ml;
                    float v = sc[mi][ni][r] * 0.125f;
                    sc[mi][ni][r] = (k > q) ? MASKVAL : v;
                }
#pragma unroll
        for (int mi = 0; mi < 2; ++mi) {
            float tm[4], ts[4], al[4];
#pragma unroll
            for (int r = 0; r < 4; ++r)
                tm[r] = fmaxf(fmaxf(sc[mi][0][r], sc[mi][1][r]), fmaxf(sc[mi][2][r], sc[mi][3][r]));
#pragma unroll
            for (int off = 1; off <= 8; off <<= 1)
#pragma unroll
                for (int r = 0; r < 4; ++r)
                    tm[r] = fmaxf(tm[r], __shfl_xor(tm[r], off, 64));
#pragma unroll
            for (int r = 0; r < 4; ++r) {
                float mn = fmaxf(mr[mi][r], tm[r]);
                al[r] = __expf(mr[mi][r] - mn);
                mr[mi][r] = mn;
            }
#pragma unroll
            for (int ni = 0; ni < 4; ++ni)
#pragma unroll
                for (int r = 0; r < 4; ++r)
                    sc[mi][ni][r] = __expf(sc[mi][ni][r] - mr[mi][r]);
#pragma unroll
            for (int r = 0; r < 4; ++r)
                ts[r] = (sc[mi][0][r] + sc[mi][1][r]) + (sc[mi][2][r] + sc[mi][3][r]);
#pragma unroll
            for (int off = 1; off <= 8; off <<= 1)
#pragma unroll
                for (int r = 0; r < 4; ++r)
                    ts[r] += __shfl_xor(ts[r], off, 64);
#pragma unroll
            for (int r = 0; r < 4; ++r) lr[mi][r] = lr[mi][r] * al[r] + ts[r];
#pragma unroll
            for (int nd = 0; nd < 4; ++nd)
#pragma unroll
                for (int r = 0; r < 4; ++r) o[mi][nd][r] *= al[r];
#pragma unroll
            for (int ni = 0; ni < 4; ++ni)
#pragma unroll
                for (int r = 0; r < 4; ++r)
                    Plds[wave][(mi * 16 + quad * 4 + r) * 64 + ni * 16 + ml] = f2bf(sc[mi][ni][r]);
        }
        asm volatile("s_waitcnt lgkmcnt(0)" ::: "memory");
        bf16x8 pf[2][2], vf[4][2];
#pragma unroll
        for (int mi = 0; mi < 2; ++mi)
#pragma unroll
            for (int kc = 0; kc < 2; ++kc)
                pf[mi][kc] = *(const bf16x8*)(&Plds[wave][(mi * 16 + ml) * 64 + kc * 32 + quad * 8]);
#pragma unroll
        for (int nd = 0; nd < 4; ++nd)
#pragma unroll
            for (int kc = 0; kc < 2; ++kc)
                vf[nd][kc] = *(const bf16x8*)(&Vt[(size_t)(bh * HD_ + nd * 16 + ml) * S_ +
                                                 kb + kc * 32 + quad * 8]);
#pragma unroll
        for (int mi = 0; mi < 2; ++mi)
#pragma unroll
            for (int nd = 0; nd < 4; ++nd)
#pragma unroll
                for (int kc = 0; kc < 2; ++kc)
                    o[mi][nd] = __builtin_amdgcn_mfma_f32_16x16x32_bf16(pf[mi][kc], vf[nd][kc],
                                                                        o[mi][nd], 0, 0, 0);
    }
#pragma unroll
    for (int mi = 0; mi < 2; ++mi) {
        float rl[4];
#pragma unroll
        for (int r = 0; r < 4; ++r) rl[r] = 1.0f / lr[mi][r];
#pragma unroll
        for (int nd = 0; nd < 4; ++nd)
#pragma unroll
            for (int r = 0; r < 4; ++r) {
                int srow = qbase + mi * 16 + quad * 4 + r;
                AO[(rowbase + srow) * D_ + h * HD_ + nd * 16 + ml] = f2bf(o[mi][nd][r] * rl[r]);
            }
    }
}

// 16B-per-thread d2d copy
__global__ __launch_bounds__(256) void copy16(const int4* __restrict__ src,
                                              int4* __restrict__ dst) {
    size_t i = (size_t)blockIdx.x * 256 + threadIdx.x;
    dst[i] = src[i];
}

extern "C" void kernel_launch(void* const* d_in, const int* in_sizes, int n_in,
                              void* d_out, int out_size, void* d_ws, size_t ws_size,
                              hipStream_t stream) {
    const float* x = (const float*)d_in[0];      // [B,S,D] f32
    const float* wqkv = (const float*)d_in[1];   // [3D,D] f32
    const float* wproj = (const float*)d_in[2];  // [D,D] f32
    float* out = (float*)d_out;                  // [B,S,D] **fp32** (reference dtype)

    // ws: only 50.33 MB (proven available in R6)
    u16* qkw = (u16*)d_ws;                        // [M, 2D]     33.55 MB
    u16* Vtw = qkw + (size_t)M_ * QK_;            // [B*H*HD, S] 16.78 MB
    // AO staged through d_out (32 MB region, scratch until final GEMM)
    u16* AOtmp = (u16*)d_out;                     // bf16 [M,D] = 16.78 MB
    u16* AOws = qkw;                              // reuses qk region after attn

    gemm_ff<<<dim3(QK_ / 128, M_ / 128), 256, 0, stream>>>(x, wqkv, qkw, QK_, D_);
    gemm_vt<<<dim3(D_ / 128, M_ / 128), 256, 0, stream>>>(x, wqkv + (size_t)QK_ * D_, Vtw, D_);
    attn<<<dim3(B_ * H_ * (S_ / 128)), 256, 0, stream>>>(qkw, Vtw, AOtmp);
    copy16<<<dim3((M_ * (size_t)D_ * 2) / (256 * 16)), 256, 0, stream>>>(
        (const int4*)AOtmp, (int4*)AOws);
    gemm_proj<<<dim3(D_ / 128, M_ / 128), 256, 0, stream>>>(AOws, wproj, out, D_, D_);
}

// Round 8
// 473.717 us; speedup vs baseline: 1.1949x; 1.1949x over previous
//
#include <hip/hip_runtime.h>

typedef unsigned short u16;
typedef unsigned int u32;

#define B_ 4
#define S_ 2048
#define D_ 1024
#define H_ 16
#define HD_ 64
#define M_ (B_ * S_)    // 8192 rows
#define QK_ (2 * D_)    // 2048 (Q|K feature stride in qk ws)

typedef __bf16 bf16x8 __attribute__((ext_vector_type(8)));
typedef float f32x4 __attribute__((ext_vector_type(4)));

#define MASKVAL (-1.0e30f)

static __device__ __forceinline__ u16 f2bf(float f) {
    union { float f; u32 u; } v; v.f = f;
    u32 u = v.u;
    u32 r = (u + 0x7FFFu + ((u >> 16) & 1u)) >> 16;  // RNE
    return (u16)r;
}

// convert 8 fp32 -> 8 bf16, store 16B to LDS
static __device__ __forceinline__ void cvt8(const float4 a, const float4 b, u16* dst) {
    union { u16 h[8]; int4 v; } pk;
    pk.h[0] = f2bf(a.x); pk.h[1] = f2bf(a.y); pk.h[2] = f2bf(a.z); pk.h[3] = f2bf(a.w);
    pk.h[4] = f2bf(b.x); pk.h[5] = f2bf(b.y); pk.h[6] = f2bf(b.z); pk.h[7] = f2bf(b.w);
    *(int4*)dst = pk.v;
}

// C[M,N](bf16) = A[M,K](f32) * B[N,K](f32)^T, fp32 accum.  (unchanged, known-good)
__global__ __launch_bounds__(256) void gemm_ff(const float* __restrict__ A,
                                               const float* __restrict__ Bw,
                                               u16* __restrict__ C,
                                               int Ndim, int Kdim) {
    __shared__ u16 Alds[128 * 72];
    __shared__ u16 Blds[128 * 72];
    const int t = threadIdx.x;
    const int bx = blockIdx.x, by = blockIdx.y;
    const int wave = t >> 6, lane = t & 63;
    const int ml = lane & 15, quad = lane >> 4;
    const int wm = (wave >> 1) * 64, wn = (wave & 1) * 64;
    const int rowA0 = by * 128, rowB0 = bx * 128;
    const int srow = t >> 3, sseg = (t & 7) * 8;

    f32x4 acc[4][4];
    const f32x4 zero = {0.f, 0.f, 0.f, 0.f};
#pragma unroll
    for (int i = 0; i < 4; ++i)
#pragma unroll
        for (int j = 0; j < 4; ++j) acc[i][j] = zero;

    for (int k0 = 0; k0 < Kdim; k0 += 64) {
        __syncthreads();
#pragma unroll
        for (int p = 0; p < 4; ++p) {
            int r = srow + p * 32;
            const float* ap = &A[(size_t)(rowA0 + r) * Kdim + k0 + sseg];
            const float* bp = &Bw[(size_t)(rowB0 + r) * Kdim + k0 + sseg];
            cvt8(*(const float4*)ap, *(const float4*)(ap + 4), &Alds[r * 72 + sseg]);
            cvt8(*(const float4*)bp, *(const float4*)(bp + 4), &Blds[r * 72 + sseg]);
        }
        __syncthreads();
#pragma unroll
        for (int kc = 0; kc < 2; ++kc) {
            bf16x8 a[4], b[4];
#pragma unroll
            for (int i = 0; i < 4; ++i)
                a[i] = *(const bf16x8*)(&Alds[(wm + i * 16 + ml) * 72 + kc * 32 + quad * 8]);
#pragma unroll
            for (int j = 0; j < 4; ++j)
                b[j] = *(const bf16x8*)(&Blds[(wn + j * 16 + ml) * 72 + kc * 32 + quad * 8]);
#pragma unroll
            for (int i = 0; i < 4; ++i)
#pragma unroll
                for (int j = 0; j < 4; ++j)
                    acc[i][j] = __builtin_amdgcn_mfma_f32_16x16x32_bf16(a[i], b[j], acc[i][j], 0, 0, 0);
        }
    }
#pragma unroll
    for (int i = 0; i < 4; ++i)
#pragma unroll
        for (int j = 0; j < 4; ++j)
#pragma unroll
            for (int r = 0; r < 4; ++r) {
                int row = rowA0 + wm + i * 16 + quad * 4 + r;
                int col = rowB0 + wn + j * 16 + ml;
                C[(size_t)row * Ndim + col] = f2bf(acc[i][j][r]);
            }
}

// V GEMM, fp32 in, transposed bf16 epilogue: Vt[(b*H+h)*64+hd][s]  (unchanged)
__global__ __launch_bounds__(256) void gemm_vt(const float* __restrict__ A,
                                               const float* __restrict__ Bw,
                                               u16* __restrict__ Vt,
                                               int Kdim) {
    __shared__ u16 Alds[128 * 72];
    __shared__ u16 Blds[128 * 72];
    const int t = threadIdx.x;
    const int bx = blockIdx.x, by = blockIdx.y;
    const int wave = t >> 6, lane = t & 63;
    const int ml = lane & 15, quad = lane >> 4;
    const int wm = (wave >> 1) * 64, wn = (wave & 1) * 64;
    const int rowA0 = by * 128, rowB0 = bx * 128;
    const int srow = t >> 3, sseg = (t & 7) * 8;

    f32x4 acc[4][4];
    const f32x4 zero = {0.f, 0.f, 0.f, 0.f};
#pragma unroll
    for (int i = 0; i < 4; ++i)
#pragma unroll
        for (int j = 0; j < 4; ++j) acc[i][j] = zero;

    for (int k0 = 0; k0 < Kdim; k0 += 64) {
        __syncthreads();
#pragma unroll
        for (int p = 0; p < 4; ++p) {
            int r = srow + p * 32;
            const float* ap = &A[(size_t)(rowA0 + r) * Kdim + k0 + sseg];
            const float* bp = &Bw[(size_t)(rowB0 + r) * Kdim + k0 + sseg];
            cvt8(*(const float4*)ap, *(const float4*)(ap + 4), &Alds[r * 72 + sseg]);
            cvt8(*(const float4*)bp, *(const float4*)(bp + 4), &Blds[r * 72 + sseg]);
        }
        __syncthreads();
#pragma unroll
        for (int kc = 0; kc < 2; ++kc) {
            bf16x8 a[4], b[4];
#pragma unroll
            for (int i = 0; i < 4; ++i)
                a[i] = *(const bf16x8*)(&Alds[(wm + i * 16 + ml) * 72 + kc * 32 + quad * 8]);
#pragma unroll
            for (int j = 0; j < 4; ++j)
                b[j] = *(const bf16x8*)(&Blds[(wn + j * 16 + ml) * 72 + kc * 32 + quad * 8]);
#pragma unroll
            for (int i = 0; i < 4; ++i)
#pragma unroll
                for (int j = 0; j < 4; ++j)
                    acc[i][j] = __builtin_amdgcn_mfma_f32_16x16x32_bf16(a[i], b[j], acc[i][j], 0, 0, 0);
        }
    }
#pragma unroll
    for (int i = 0; i < 4; ++i)
#pragma unroll
        for (int j = 0; j < 4; ++j) {
            int row0 = rowA0 + wm + i * 16 + quad * 4;  // token, multiple of 4
            int col = rowB0 + wn + j * 16 + ml;         // V feature
            int b = row0 >> 11;
            int s0 = row0 & (S_ - 1);
            union { u16 h[4]; ushort4 v; } pk;
#pragma unroll
            for (int r = 0; r < 4; ++r) pk.h[r] = f2bf(acc[i][j][r]);
            *(ushort4*)(&Vt[((size_t)(b * D_ + col)) * S_ + s0]) = pk.v;
        }
}

// Proj GEMM: A bf16 [M,K], B fp32 [N,K], C fp32 out  (unchanged)
__global__ __launch_bounds__(256) void gemm_proj(const u16* __restrict__ A,
                                                 const float* __restrict__ Bw,
                                                 float* __restrict__ C,
                                                 int Ndim, int Kdim) {
    __shared__ u16 Alds[128 * 72];
    __shared__ u16 Blds[128 * 72];
    const int t = threadIdx.x;
    const int bx = blockIdx.x, by = blockIdx.y;
    const int wave = t >> 6, lane = t & 63;
    const int ml = lane & 15, quad = lane >> 4;
    const int wm = (wave >> 1) * 64, wn = (wave & 1) * 64;
    const int rowA0 = by * 128, rowB0 = bx * 128;
    const int srow = t >> 3, sseg = (t & 7) * 8;

    f32x4 acc[4][4];
    const f32x4 zero = {0.f, 0.f, 0.f, 0.f};
#pragma unroll
    for (int i = 0; i < 4; ++i)
#pragma unroll
        for (int j = 0; j < 4; ++j) acc[i][j] = zero;

    for (int k0 = 0; k0 < Kdim; k0 += 64) {
        __syncthreads();
#pragma unroll
        for (int p = 0; p < 4; ++p) {
            int r = srow + p * 32;
            *(int4*)(&Alds[r * 72 + sseg]) =
                *(const int4*)(&A[(size_t)(rowA0 + r) * Kdim + k0 + sseg]);
            const float* bp = &Bw[(size_t)(rowB0 + r) * Kdim + k0 + sseg];
            cvt8(*(const float4*)bp, *(const float4*)(bp + 4), &Blds[r * 72 + sseg]);
        }
        __syncthreads();
#pragma unroll
        for (int kc = 0; kc < 2; ++kc) {
            bf16x8 a[4], b[4];
#pragma unroll
            for (int i = 0; i < 4; ++i)
                a[i] = *(const bf16x8*)(&Alds[(wm + i * 16 + ml) * 72 + kc * 32 + quad * 8]);
#pragma unroll
            for (int j = 0; j < 4; ++j)
                b[j] = *(const bf16x8*)(&Blds[(wn + j * 16 + ml) * 72 + kc * 32 + quad * 8]);
#pragma unroll
            for (int i = 0; i < 4; ++i)
#pragma unroll
                for (int j = 0; j < 4; ++j)
                    acc[i][j] = __builtin_amdgcn_mfma_f32_16x16x32_bf16(a[i], b[j], acc[i][j], 0, 0, 0);
        }
    }
#pragma unroll
    for (int i = 0; i < 4; ++i)
#pragma unroll
        for (int j = 0; j < 4; ++j)
#pragma unroll
            for (int r = 0; r < 4; ++r) {
                int row = rowA0 + wm + i * 16 + quad * 4 + r;
                int col = rowB0 + wn + j * 16 + ml;
                C[(size_t)row * Ndim + col] = acc[i][j][r];   // fp32 store
            }
}

// attn2: uniform-work flash attention.
// Grid 512: bid = j*64 + bh; block handles q-tiles {j, 15-j} of head bh.
// K/V tiles staged cooperatively in LDS (shared by 4 waves); per-lane partial
// row-sums with delayed shuffle reduction; P round-trip via padded LDS.
__global__ __launch_bounds__(256, 2) void attn2(const u16* __restrict__ qk,
                                                const u16* __restrict__ Vt,
                                                u16* __restrict__ AO) {
    __shared__ u16 Klds[64][68];   // pad 68: conflict-free b128 frag reads
    __shared__ u16 Vlds[64][68];
    __shared__ u16 Plds[4][32 * 68];
    const int t = threadIdx.x;
    const int wave = t >> 6, lane = t & 63;
    const int ml = lane & 15, quad = lane >> 4;
    const int j = blockIdx.x >> 6;       // 0..7
    const int bh = blockIdx.x & 63;      // head id; bid%8 = bh%8 -> XCD-pinned heads
    const int b = bh >> 4, h = bh & 15;
    const size_t rowbase = (size_t)b * S_;
    const int sr = t >> 3, sseg = (t & 7) * 8;

    int qw[2], ktw[2];
    qw[0] = j * 128 + wave * 32;
    qw[1] = (15 - j) * 128 + wave * 32;
    ktw[0] = (qw[0] + 31) >> 6;
    ktw[1] = (qw[1] + 31) >> 6;
    const int ktmax = ((15 - j) * 128 + 127) >> 6;

    bf16x8 qf[2][2][2];   // [tile][mi][kc]
#pragma unroll
    for (int T = 0; T < 2; ++T)
#pragma unroll
        for (int mi = 0; mi < 2; ++mi)
#pragma unroll
            for (int kc = 0; kc < 2; ++kc)
                qf[T][mi][kc] = *(const bf16x8*)(&qk[(rowbase + qw[T] + mi * 16 + ml) * QK_ +
                                                     h * HD_ + kc * 32 + quad * 8]);

    f32x4 o[2][2][4];
    float m[2][2][4], ls[2][2][4];
    const f32x4 zero = {0.f, 0.f, 0.f, 0.f};
#pragma unroll
    for (int T = 0; T < 2; ++T)
#pragma unroll
        for (int mi = 0; mi < 2; ++mi) {
#pragma unroll
            for (int nd = 0; nd < 4; ++nd) o[T][mi][nd] = zero;
#pragma unroll
            for (int r = 0; r < 4; ++r) { m[T][mi][r] = MASKVAL; ls[T][mi][r] = 0.f; }
        }

    for (int kt = 0; kt <= ktmax; ++kt) {
        const int kb = kt * 64;
        __syncthreads();
#pragma unroll
        for (int p = 0; p < 2; ++p) {
            int r = sr + p * 32;
            *(int4*)(&Klds[r][sseg]) =
                *(const int4*)(&qk[(rowbase + kb + r) * QK_ + D_ + h * HD_ + sseg]);
            *(int4*)(&Vlds[r][sseg]) =
                *(const int4*)(&Vt[(size_t)(bh * HD_ + r) * S_ + kb + sseg]);
        }
        __syncthreads();
        if (kt > ktw[1]) continue;   // this wave idle this round (barriers stay matched)

        bf16x8 kf[4][2], vf[4][2];
#pragma unroll
        for (int ni = 0; ni < 4; ++ni)
#pragma unroll
            for (int kc = 0; kc < 2; ++kc) {
                kf[ni][kc] = *(const bf16x8*)(&Klds[ni * 16 + ml][kc * 32 + quad * 8]);
                vf[ni][kc] = *(const bf16x8*)(&Vlds[ni * 16 + ml][kc * 32 + quad * 8]);
            }

#pragma unroll
        for (int T = 0; T < 2; ++T) {
            if (kt > ktw[T]) continue;
            const int qT = qw[T];
            f32x4 sc[2][4];
#pragma unroll
            for (int mi = 0; mi < 2; ++mi)
#pragma unroll
                for (int ni = 0; ni < 4; ++ni) {
                    f32x4 s = zero;
#pragma unroll
                    for (int kc = 0; kc < 2; ++kc)
                        s = __builtin_amdgcn_mfma_f32_16x16x32_bf16(qf[T][mi][kc], kf[ni][kc], s, 0, 0, 0);
                    sc[mi][ni] = s;
                }
            if (kb + 63 <= qT) {   // interior tile: no masking VALU
#pragma unroll
                for (int mi = 0; mi < 2; ++mi)
#pragma unroll
                    for (int ni = 0; ni < 4; ++ni)
#pragma unroll
                        for (int r = 0; r < 4; ++r) sc[mi][ni][r] *= 0.125f;
            } else {
#pragma unroll
                for (int mi = 0; mi < 2; ++mi)
#pragma unroll
                    for (int ni = 0; ni < 4; ++ni)
#pragma unroll
                        for (int r = 0; r < 4; ++r) {
                            int q = qT + mi * 16 + quad * 4 + r;
                            int k = kb + ni * 16 + ml;
                            float v = sc[mi][ni][r] * 0.125f;
                            sc[mi][ni][r] = (k > q) ? MASKVAL : v;
                        }
            }
#pragma unroll
            for (int mi = 0; mi < 2; ++mi) {
                float tm[4], al[4];
#pragma unroll
                for (int r = 0; r < 4; ++r)
                    tm[r] = fmaxf(fmaxf(sc[mi][0][r], sc[mi][1][r]),
                                  fmaxf(sc[mi][2][r], sc[mi][3][r]));
#pragma unroll
                for (int off = 1; off <= 8; off <<= 1)
#pragma unroll
                    for (int r = 0; r < 4; ++r)
                        tm[r] = fmaxf(tm[r], __shfl_xor(tm[r], off, 64));
#pragma unroll
                for (int r = 0; r < 4; ++r) {
                    float mn = fmaxf(m[T][mi][r], tm[r]);
                    al[r] = __expf(m[T][mi][r] - mn);
                    m[T][mi][r] = mn;
                }
#pragma unroll
                for (int ni = 0; ni < 4; ++ni)
#pragma unroll
                    for (int r = 0; r < 4; ++r)
                        sc[mi][ni][r] = __expf(sc[mi][ni][r] - m[T][mi][r]);
#pragma unroll
                for (int r = 0; r < 4; ++r)
                    ls[T][mi][r] = ls[T][mi][r] * al[r] +
                                   ((sc[mi][0][r] + sc[mi][1][r]) + (sc[mi][2][r] + sc[mi][3][r]));
#pragma unroll
                for (int nd = 0; nd < 4; ++nd)
#pragma unroll
                    for (int r = 0; r < 4; ++r) o[T][mi][nd][r] *= al[r];
#pragma unroll
                for (int ni = 0; ni < 4; ++ni)
#pragma unroll
                    for (int r = 0; r < 4; ++r)
                        Plds[wave][(mi * 16 + quad * 4 + r) * 68 + ni * 16 + ml] = f2bf(sc[mi][ni][r]);
            }
            asm volatile("s_waitcnt lgkmcnt(0)" ::: "memory");
            bf16x8 pf[2][2];
#pragma unroll
            for (int mi = 0; mi < 2; ++mi)
#pragma unroll
                for (int kc = 0; kc < 2; ++kc)
                    pf[mi][kc] = *(const bf16x8*)(&Plds[wave][(mi * 16 + ml) * 68 + kc * 32 + quad * 8]);
#pragma unroll
            for (int mi = 0; mi < 2; ++mi)
#pragma unroll
                for (int nd = 0; nd < 4; ++nd)
#pragma unroll
                    for (int kc = 0; kc < 2; ++kc)
                        o[T][mi][nd] = __builtin_amdgcn_mfma_f32_16x16x32_bf16(pf[mi][kc], vf[nd][kc],
                                                                               o[T][mi][nd], 0, 0, 0);
        }
    }
    // epilogue: delayed l reduction + normalize + store
#pragma unroll
    for (int T = 0; T < 2; ++T)
#pragma unroll
        for (int mi = 0; mi < 2; ++mi) {
            float s4[4], rl[4];
#pragma unroll
            for (int r = 0; r < 4; ++r) s4[r] = ls[T][mi][r];
#pragma unroll
            for (int off = 1; off <= 8; off <<= 1)
#pragma unroll
                for (int r = 0; r < 4; ++r) s4[r] += __shfl_xor(s4[r], off, 64);
#pragma unroll
            for (int r = 0; r < 4; ++r) rl[r] = 1.0f / s4[r];
#pragma unroll
            for (int nd = 0; nd < 4; ++nd)
#pragma unroll
                for (int r = 0; r < 4; ++r) {
                    int srow = qw[T] + mi * 16 + quad * 4 + r;
                    AO[(rowbase + srow) * D_ + h * HD_ + nd * 16 + ml] =
                        f2bf(o[T][mi][nd][r] * rl[r]);
                }
        }
}

// 16B-per-thread d2d copy
__global__ __launch_bounds__(256) void copy16(const int4* __restrict__ src,
                                              int4* __restrict__ dst) {
    size_t i = (size_t)blockIdx.x * 256 + threadIdx.x;
    dst[i] = src[i];
}

extern "C" void kernel_launch(void* const* d_in, const int* in_sizes, int n_in,
                              void* d_out, int out_size, void* d_ws, size_t ws_size,
                              hipStream_t stream) {
    const float* x = (const float*)d_in[0];      // [B,S,D] f32
    const float* wqkv = (const float*)d_in[1];   // [3D,D] f32
    const float* wproj = (const float*)d_in[2];  // [D,D] f32
    float* out = (float*)d_out;                  // [B,S,D] fp32

    u16* qkw = (u16*)d_ws;                        // [M, 2D]     33.55 MB
    u16* Vtw = qkw + (size_t)M_ * QK_;            // [B*H*HD, S] 16.78 MB
    u16* AOtmp = (u16*)d_out;                     // bf16 [M,D] scratch in d_out
    u16* AOws = qkw;                              // reuses qk region after attn

    gemm_ff<<<dim3(QK_ / 128, M_ / 128), 256, 0, stream>>>(x, wqkv, qkw, QK_, D_);
    gemm_vt<<<dim3(D_ / 128, M_ / 128), 256, 0, stream>>>(x, wqkv + (size_t)QK_ * D_, Vtw, D_);
    attn2<<<dim3(512), 256, 0, stream>>>(qkw, Vtw, AOtmp);
    copy16<<<dim3((M_ * (size_t)D_ * 2) / (256 * 16)), 256, 0, stream>>>(
        (const int4*)AOtmp, (int4*)AOws);
    gemm_proj<<<dim3(D_ / 128, M_ / 128), 256, 0, stream>>>(AOws, wproj, out, D_, D_);
}